// Round 17
// baseline (342.502 us; speedup 1.0000x reference)
//
#include <hip/hip_runtime.h>
#include <hip/hip_bf16.h>
#include <math.h>

#define N_NODES  100000
#define N_EDGES  1600000
#define N_GRAPHS 1000
#define NPG      100
#define NBKT     391          // ceil(100000/256); bucket = dst >> 8
#define BCAP     5120         // fixed bucket capacity (mean 4092, +16 sigma)
#define EPB      16384        // edges per block in binning (fat blocks: less bkt_cur contention)
#define NBE      ((N_EDGES + EPB - 1) / EPB)   // 98 edge blocks
#define GBA      ((N_NODES + 63) / 64)         // 1563 fusedA blocks

typedef float  f32x4 __attribute__((ext_vector_type(4)));
typedef short  s16x8 __attribute__((ext_vector_type(8)));

__device__ __forceinline__ float elu_f(float x) {
    return x > 0.0f ? x : expm1f(x);
}
__device__ __forceinline__ float bf2f(unsigned int u16) {
    union { unsigned int i; float f; } v; v.i = u16 << 16; return v.f;
}
__device__ __forceinline__ unsigned short f2bf(float f) {
    __hip_bfloat16 h = __float2bfloat16(f);
    return *reinterpret_cast<unsigned short*>(&h);
}
__device__ __forceinline__ s16x8 cvt8(const float4& a, const float4& b) {
    s16x8 o;
    o[0]=(short)f2bf(a.x); o[1]=(short)f2bf(a.y); o[2]=(short)f2bf(a.z); o[3]=(short)f2bf(a.w);
    o[4]=(short)f2bf(b.x); o[5]=(short)f2bf(b.y); o[6]=(short)f2bf(b.z); o[7]=(short)f2bf(b.w);
    return o;
}

// ---------------- setup: bucket cursors + weight bf16 conversion ----------------
// wb layout: [0,8192)=W0[128x64]; [8192,16384)=W1c[64x128]; [16384,20480)=W1w[32x128];
//            [20480,24576)=W2c[32x128]; [24576,28672)=W2w[32x128]
__global__ __launch_bounds__(512) void setup_k(
    int* __restrict__ bkt_cur,
    const float* __restrict__ w0, const float* __restrict__ w1c, const float* __restrict__ w1w,
    const float* __restrict__ w2c, const float* __restrict__ w2w, unsigned short* __restrict__ wb)
{
    int t = threadIdx.x;
    if (blockIdx.x == 0 && t < NBKT) bkt_cur[t] = t * BCAP;
    int i = blockIdx.x * 512 + t;
    float v;
    if (i < 8192)       v = w0[i];
    else if (i < 16384) v = w1c[i - 8192];
    else if (i < 20480) v = w1w[i - 16384];
    else if (i < 24576) v = w2c[i - 20480];
    else if (i < 28672) v = w2w[i - 24576];
    else return;
    wb[i] = f2bf(v);
}

// ---------------- merged: binscatter (blocks [0,NBE)) || fusedA (blocks [NBE,NBE+GBA)) ----------------
// binscatter: scatter packed (src<<8|dstLocal) into fixed-capacity bucket regions
// fusedA: h1 = elu(x@W0^T+b0) [LDS]; b1 = h1@Wc^T bf16 (UNSCALED); w1 = h1@Ww^T+bw fp32
__global__ __launch_bounds__(256) void scatterA_k(
    const float* __restrict__ x, const unsigned short* __restrict__ wb,
    const float* __restrict__ b0, const float* __restrict__ bw,
    unsigned short* __restrict__ c1out, float* __restrict__ w1out, int M,
    const int* __restrict__ ei, int* __restrict__ bkt_cur, unsigned int* __restrict__ pairs)
{
    __shared__ union {
        struct { int h[NBKT]; int base[NBKT]; } sc;
        unsigned short hT[64][136];
    } u;

    const int t = threadIdx.x;

    if (blockIdx.x < NBE) {
        // ---- binscatter branch (dispatched first; overlaps fusedA) ----
        const int eb = blockIdx.x;
        int* h = u.sc.h;
        int* base = u.sc.base;
        for (int i = t; i < NBKT; i += 256) h[i] = 0;
        __syncthreads();
        const int4* src4 = (const int4*)ei;
        const int4* dst4 = (const int4*)(ei + N_EDGES);
        int i0 = eb * (EPB / 4);
        for (int i = t; i < EPB / 4; i += 256) {
            int g = i0 + i;
            if (g < N_EDGES / 4) {
                int4 d = dst4[g];
                atomicAdd(&h[d.x >> 8], 1);
                atomicAdd(&h[d.y >> 8], 1);
                atomicAdd(&h[d.z >> 8], 1);
                atomicAdd(&h[d.w >> 8], 1);
            }
        }
        __syncthreads();
        for (int i = t; i < NBKT; i += 256) {
            int c = h[i];
            base[i] = c ? atomicAdd(&bkt_cur[i], c) : 0;
            h[i] = 0;
        }
        __syncthreads();
        for (int i = t; i < EPB / 4; i += 256) {
            int g = i0 + i;
            if (g < N_EDGES / 4) {
                int4 s4 = src4[g];
                int4 d4 = dst4[g];
                int b, r;
                b = d4.x >> 8; r = atomicAdd(&h[b], 1); pairs[base[b] + r] = ((unsigned)s4.x << 8) | (d4.x & 255);
                b = d4.y >> 8; r = atomicAdd(&h[b], 1); pairs[base[b] + r] = ((unsigned)s4.y << 8) | (d4.y & 255);
                b = d4.z >> 8; r = atomicAdd(&h[b], 1); pairs[base[b] + r] = ((unsigned)s4.z << 8) | (d4.z & 255);
                b = d4.w >> 8; r = atomicAdd(&h[b], 1); pairs[base[b] + r] = ((unsigned)s4.w << 8) | (d4.w & 255);
            }
        }
        return;
    }

    // ---- fusedA branch ----
    const unsigned short* W0b = wb;            // [128][64]
    const unsigned short* Wcb = wb + 8192;     // [64][128]
    const unsigned short* Wwb = wb + 16384;    // [32][128]

    const int wave = t >> 6, lane = t & 63;
    const int lr = lane & 15, lk = lane >> 4;
    const int blockRow = (blockIdx.x - NBE) * 64;

    // phase 1: h tile [64x128] = x[64x64] @ W0[128x64]^T
    {
        const int wr = wave >> 1, wc = wave & 1;
        f32x4 acc[2][4];
        #pragma unroll
        for (int rt = 0; rt < 2; ++rt)
            #pragma unroll
            for (int ct = 0; ct < 4; ++ct) acc[rt][ct] = (f32x4){0.f,0.f,0.f,0.f};

        #pragma unroll
        for (int kt = 0; kt < 2; ++kt) {
            const int k0 = kt * 32 + lk * 8;
            s16x8 afr[2];
            #pragma unroll
            for (int rt = 0; rt < 2; ++rt) {
                int r = blockRow + (wr * 2 + rt) * 16 + lr;
                r = (r < M) ? r : (M - 1);
                const float* ap = x + (size_t)r * 64 + k0;
                afr[rt] = cvt8(*(const float4*)ap, *(const float4*)(ap + 4));
            }
            s16x8 bfr[4];
            #pragma unroll
            for (int ct = 0; ct < 4; ++ct) {
                int n = (wc * 4 + ct) * 16 + lr;
                bfr[ct] = *(const s16x8*)(W0b + (size_t)n * 64 + k0);
            }
            #pragma unroll
            for (int rt = 0; rt < 2; ++rt)
                #pragma unroll
                for (int ct = 0; ct < 4; ++ct)
                    acc[rt][ct] = __builtin_amdgcn_mfma_f32_16x16x32_bf16(afr[rt], bfr[ct], acc[rt][ct], 0, 0, 0);
        }
        #pragma unroll
        for (int rt = 0; rt < 2; ++rt) {
            int lmb = (wr * 2 + rt) * 16 + lk * 4;
            #pragma unroll
            for (int j = 0; j < 4; ++j) {
                #pragma unroll
                for (int ct = 0; ct < 4; ++ct) {
                    int n = (wc * 4 + ct) * 16 + lr;
                    u.hT[lmb + j][n] = f2bf(elu_f(acc[rt][ct][j] + b0[n]));
                }
            }
        }
    }
    __syncthreads();

    // phase 2: [64x128] @ [96x128]^T ; cols 0..63 -> b1 (unscaled), 64..95 -> w1
    {
        f32x4 acc[6];
        #pragma unroll
        for (int ct = 0; ct < 6; ++ct) acc[ct] = (f32x4){0.f,0.f,0.f,0.f};
        #pragma unroll
        for (int kt = 0; kt < 4; ++kt) {
            const int k0 = kt * 32 + lk * 8;
            s16x8 af = *(const s16x8*)&u.hT[wave * 16 + lr][k0];
            #pragma unroll
            for (int ct = 0; ct < 6; ++ct) {
                int n = ct * 16 + lr;
                const unsigned short* wp = (n < 64) ? (Wcb + (size_t)n * 128 + k0)
                                                    : (Wwb + (size_t)(n - 64) * 128 + k0);
                acc[ct] = __builtin_amdgcn_mfma_f32_16x16x32_bf16(af, *(const s16x8*)wp, acc[ct], 0, 0, 0);
            }
        }
        int mbase = blockRow + wave * 16 + lk * 4;
        #pragma unroll
        for (int j = 0; j < 4; ++j) {
            int m = mbase + j;
            if (m >= M) continue;
            #pragma unroll
            for (int ct = 0; ct < 6; ++ct) {
                int n = ct * 16 + lr;
                float v = acc[ct][j];
                if (n < 64) c1out[(size_t)m * 64 + n] = f2bf(v);
                else        w1out[(size_t)m * 32 + (n - 64)] = v + bw[n - 64];
            }
        }
    }
}

// ---------------- bucket CSR: per-node counts/starts/dis + srclist ----------------
__global__ __launch_bounds__(256) void bucket_csr_k(const unsigned int* __restrict__ pairs,
                                                    const int* __restrict__ bkt_cur,
                                                    int* __restrict__ starts,
                                                    int* __restrict__ cnt,
                                                    float* __restrict__ dis,
                                                    int* __restrict__ srclist)
{
    __shared__ int s[256];
    __shared__ int cur[256];
    const int b = blockIdx.x, t = threadIdx.x;
    const int lo = b * BCAP;
    const int hi = bkt_cur[b];
    const int n0 = b << 8;
    const int nn = min(256, N_NODES - n0);

    s[t] = 0;
    __syncthreads();
    for (int i = lo + t; i < hi; i += 256) {
        unsigned int p = pairs[i];
        atomicAdd(&s[p & 255], 1);
    }
    __syncthreads();
    int v = s[t];
    __syncthreads();
    s[t] = v;
    __syncthreads();
    #pragma unroll
    for (int off = 1; off < 256; off <<= 1) {
        int u = (t >= off) ? s[t - off] : 0;
        __syncthreads();
        s[t] += u;
        __syncthreads();
    }
    int ex = lo + s[t] - v;
    if (t < nn) {
        starts[n0 + t] = ex;
        cnt[n0 + t] = v;
        dis[n0 + t] = rsqrtf(1.0f + (float)v);
    }
    cur[t] = ex;
    __syncthreads();
    for (int i = lo + t; i < hi; i += 256) {
        unsigned int p = pairs[i];
        int pos = atomicAdd(&cur[p & 255], 1);
        srclist[pos] = (int)(p >> 8);
    }
}

// ---------------- layer-2 fused GEMM: c2 = dis*(h2@Wc^T) bf16 ; w2 = h2@Ww^T+bw fp32 ----------------
__global__ __launch_bounds__(256) void mgemmL2_k(
    const unsigned short* __restrict__ Ab, const unsigned short* __restrict__ wb,
    const float* __restrict__ bw, const float* __restrict__ dis,
    unsigned short* __restrict__ c2out, float* __restrict__ w2out, int M)
{
    const unsigned short* Wcb = wb + 20480;    // [32][128]
    const unsigned short* Wwb = wb + 24576;    // [32][128]

    const int t = threadIdx.x;
    const int wave = t >> 6, lane = t & 63;
    const int wr = wave >> 1, wc = wave & 1;
    const int lr = lane & 15, lk = lane >> 4;
    const int blockRow = blockIdx.x * 64;

    f32x4 acc[2][2];
    #pragma unroll
    for (int rt = 0; rt < 2; ++rt)
        #pragma unroll
        for (int ct = 0; ct < 2; ++ct) acc[rt][ct] = (f32x4){0.f,0.f,0.f,0.f};

    #pragma unroll
    for (int kt = 0; kt < 4; ++kt) {
        const int k0 = kt * 32 + lk * 8;
        s16x8 afr[2];
        #pragma unroll
        for (int rt = 0; rt < 2; ++rt) {
            int r = blockRow + (wr * 2 + rt) * 16 + lr;
            r = (r < M) ? r : (M - 1);
            afr[rt] = *(const s16x8*)(Ab + (size_t)r * 128 + k0);
        }
        s16x8 bfr[2];
        #pragma unroll
        for (int ct = 0; ct < 2; ++ct) {
            int n = (wc * 2 + ct) * 16 + lr;
            const unsigned short* wp = (n < 32) ? (Wcb + (size_t)n * 128 + k0)
                                                : (Wwb + (size_t)(n - 32) * 128 + k0);
            bfr[ct] = *(const s16x8*)wp;
        }
        #pragma unroll
        for (int rt = 0; rt < 2; ++rt)
            #pragma unroll
            for (int ct = 0; ct < 2; ++ct)
                acc[rt][ct] = __builtin_amdgcn_mfma_f32_16x16x32_bf16(afr[rt], bfr[ct], acc[rt][ct], 0, 0, 0);
    }

    #pragma unroll
    for (int rt = 0; rt < 2; ++rt) {
        int mbase = blockRow + (wr * 2 + rt) * 16 + lk * 4;
        #pragma unroll
        for (int j = 0; j < 4; ++j) {
            int m = mbase + j;
            if (m >= M) continue;
            float dsc = dis[m];
            #pragma unroll
            for (int ct = 0; ct < 2; ++ct) {
                int n = (wc * 2 + ct) * 16 + lr;
                float v = acc[rt][ct][j];
                if (n < 32) c2out[(size_t)m * 32 + n] = f2bf(dsc * v);
                else        w2out[(size_t)m * 32 + (n - 32)] = v + bw[n - 32];
            }
        }
    }
}

// ---------------- layer-1 gather (wave/node, 4 edge slots) + combine + elu ----------------
// c holds UNSCALED b1; dis applied per gathered row here.
__global__ __launch_bounds__(256) void gather1_k(
    const int* __restrict__ starts, const int* __restrict__ cnt,
    const int* __restrict__ srclist, const unsigned short* __restrict__ c,
    const float* __restrict__ w1, const float* __restrict__ dis,
    const float* __restrict__ bias, unsigned short* __restrict__ h2b)
{
    __shared__ float aggS[4][68];

    const int t = threadIdx.x;
    const int nn   = t >> 6;
    const int lane = t & 63;
    const int q    = lane & 15;
    const int slot = lane >> 4;
    const int n    = blockIdx.x * 4 + nn;

    const int s0 = starts[n];
    const int cn = cnt[n];
    float a0 = 0.f, a1 = 0.f, a2 = 0.f, a3 = 0.f;
    if (slot == 0) {                                    // self term: dis[n]*b[n]
        float dsn = dis[n];
        uint2 u = *(const uint2*)(c + (size_t)n * 64 + q * 4);
        a0 = dsn * bf2f(u.x & 0xffff); a1 = dsn * bf2f(u.x >> 16);
        a2 = dsn * bf2f(u.y & 0xffff); a3 = dsn * bf2f(u.y >> 16);
    }
    for (int j = slot; j < cn; j += 4) {
        int src = srclist[s0 + j];
        float ds = dis[src];
        uint2 u = *(const uint2*)(c + (size_t)src * 64 + q * 4);
        a0 = fmaf(ds, bf2f(u.x & 0xffff), a0); a1 = fmaf(ds, bf2f(u.x >> 16), a1);
        a2 = fmaf(ds, bf2f(u.y & 0xffff), a2); a3 = fmaf(ds, bf2f(u.y >> 16), a3);
    }
    a0 += __shfl_xor(a0, 16, 64); a0 += __shfl_xor(a0, 32, 64);
    a1 += __shfl_xor(a1, 16, 64); a1 += __shfl_xor(a1, 32, 64);
    a2 += __shfl_xor(a2, 16, 64); a2 += __shfl_xor(a2, 32, 64);
    a3 += __shfl_xor(a3, 16, 64); a3 += __shfl_xor(a3, 32, 64);
    if (slot == 0) {
        aggS[nn][q * 4 + 0] = a0;
        aggS[nn][q * 4 + 1] = a1;
        aggS[nn][q * 4 + 2] = a2;
        aggS[nn][q * 4 + 3] = a3;
    }
    __syncthreads();

    const float dn = dis[n];
    const float* wr = w1 + (size_t)n * 32;
    unsigned short* out = h2b + (size_t)n * 128;
    #pragma unroll
    for (int r = 0; r < 2; ++r) {
        int j = r * 64 + lane;
        int hh = j >> 4, f = j & 15;
        float4 wv = *(const float4*)(wr + hh * 4);
        float s = wv.x * aggS[nn][0 * 16 + f] + wv.y * aggS[nn][1 * 16 + f]
                + wv.z * aggS[nn][2 * 16 + f] + wv.w * aggS[nn][3 * 16 + f];
        out[j] = f2bf(elu_f(s * dn + bias[j]));
    }
}

// ---------------- fused layer-2 gather + L2 norm + graph tail (block per graph) ----------------
__global__ __launch_bounds__(256) void graphfused_k(
    const int* __restrict__ starts, const int* __restrict__ cnt,
    const int* __restrict__ srclist, const unsigned short* __restrict__ c,
    const float* __restrict__ w2, const float* __restrict__ dis,
    const float* __restrict__ bias,
    const float* __restrict__ z_e, const float* __restrict__ aw, const float* __restrict__ ab,
    const float* __restrict__ fcgw, const float* __restrict__ fcgb,
    const float* __restrict__ fccgw, const float* __restrict__ fccgb,
    float* __restrict__ hout, float* __restrict__ z_a, float* __restrict__ z_c)
{
    __shared__ float Hs[NPG * 64];
    __shared__ float aggS[4][36];
    __shared__ float sumh[64], wsh[64], lg[NPG], ex[NPG];
    __shared__ float red[2];

    const int g = blockIdx.x, t = threadIdx.x;
    const int wave = t >> 6, lane = t & 63;
    const int q    = lane & 15;
    const int slot = lane >> 4;

    // ---- phase A: gather + combine + elu + L2-norm for this graph's 100 nodes ----
    for (int it = 0; it < 25; ++it) {
        const int ln = it * 4 + wave;              // local node 0..99
        const int n  = g * NPG + ln;
        const int s0 = starts[n];
        const int cn = cnt[n];
        float a0 = 0.f, a1 = 0.f;
        if (slot == 0) {
            unsigned int u = *(const unsigned int*)(c + (size_t)n * 32 + q * 2);
            a0 = bf2f(u & 0xffff); a1 = bf2f(u >> 16);
        }
        for (int j = slot; j < cn; j += 4) {
            int src = srclist[s0 + j];
            unsigned int u = *(const unsigned int*)(c + (size_t)src * 32 + q * 2);
            a0 += bf2f(u & 0xffff); a1 += bf2f(u >> 16);
        }
        a0 += __shfl_xor(a0, 16, 64); a0 += __shfl_xor(a0, 32, 64);
        a1 += __shfl_xor(a1, 16, 64); a1 += __shfl_xor(a1, 32, 64);
        if (slot == 0) {
            aggS[wave][q * 2 + 0] = a0;
            aggS[wave][q * 2 + 1] = a1;
        }
        // aggS is wave-private: same-wave DS ordering, no barrier needed (R11 pattern)
        const float dn = dis[n];
        const int hh = lane >> 3, f = lane & 7;
        float4 wv = *(const float4*)(w2 + (size_t)n * 32 + hh * 4);
        float s = wv.x * aggS[wave][0 * 8 + f] + wv.y * aggS[wave][1 * 8 + f]
                + wv.z * aggS[wave][2 * 8 + f] + wv.w * aggS[wave][3 * 8 + f];
        float sv = elu_f(s * dn + bias[lane]);

        float tot = sv * sv;
        #pragma unroll
        for (int o = 1; o < 64; o <<= 1) tot += __shfl_xor(tot, o, 64);
        float inv = 1.0f / fmaxf(sqrtf(tot), 1e-12f);
        float hv = sv * inv;
        hout[(size_t)n * 64 + lane] = hv;
        Hs[ln * 64 + lane] = hv;
    }
    __syncthreads();

    // ---- phase B: z_a, attention softmax, z_c (as graph_k) ----
    if (t < 64) {
        float s = 0.0f;
        for (int n = 0; n < NPG; ++n) s += Hs[n * 64 + t];
        sumh[t] = s;
    }
    __syncthreads();

    if (t < 64) {
        float acc = fcgb[t];
        for (int f = 0; f < 64; ++f) acc = fmaf(sumh[f], fcgw[t * 64 + f], acc);
        z_a[(size_t)g * 64 + t] = acc;
    }
    if (t < NPG) {
        float zd = 0.0f;
        for (int qq = 0; qq < 32; ++qq) zd = fmaf(z_e[(size_t)g * 32 + qq], aw[64 + qq], zd);
        float dot = 0.0f;
        for (int k0 = 0; k0 < 64; ++k0) {
            int k = (k0 + t) & 63;
            dot = fmaf(Hs[t * 64 + k], aw[k], dot);
        }
        lg[t] = dot + zd + ab[0] + 1e-16f;
    }
    __syncthreads();

    if (t < 64) {
        float m = -INFINITY;
        for (int n = t; n < NPG; n += 64) m = fmaxf(m, lg[n]);
        #pragma unroll
        for (int o = 1; o < 64; o <<= 1) m = fmaxf(m, __shfl_xor(m, o, 64));
        if (t == 0) red[0] = m;
    }
    __syncthreads();
    float m = red[0];
    if (t < NPG) ex[t] = expf(lg[t] - m);
    __syncthreads();
    if (t < 64) {
        float s = 0.0f;
        for (int n = t; n < NPG; n += 64) s += ex[n];
        #pragma unroll
        for (int o = 1; o < 64; o <<= 1) s += __shfl_xor(s, o, 64);
        if (t == 0) red[1] = s + 1e-16f;
    }
    __syncthreads();
    float inv_denom = 1.0f / red[1];
    if (t < 64) {
        float a = 0.0f;
        for (int n = 0; n < NPG; ++n) a = fmaf(ex[n], Hs[n * 64 + t], a);
        wsh[t] = a * inv_denom;
    }
    __syncthreads();
    if (t < 64) {
        float acc = fccgb[t];
        for (int f = 0; f < 64; ++f) acc = fmaf(wsh[f], fccgw[t * 64 + f], acc);
        z_c[(size_t)g * 64 + t] = acc;
    }
}

extern "C" void kernel_launch(void* const* d_in, const int* in_sizes, int n_in,
                              void* d_out, int out_size, void* d_ws, size_t ws_size,
                              hipStream_t stream)
{
    const float* x     = (const float*)d_in[0];
    const int*   ei    = (const int*)d_in[1];
    const float* z_e   = (const float*)d_in[4];
    const float* nfc_w = (const float*)d_in[5];
    const float* nfc_b = (const float*)d_in[6];
    const float* g1bw  = (const float*)d_in[7];
    const float* g1cw  = (const float*)d_in[8];
    const float* g1cb  = (const float*)d_in[9];
    const float* g1b   = (const float*)d_in[10];
    const float* g2bw  = (const float*)d_in[11];
    const float* g2cw  = (const float*)d_in[12];
    const float* g2cb  = (const float*)d_in[13];
    const float* g2b   = (const float*)d_in[14];
    const float* aw    = (const float*)d_in[15];
    const float* ab    = (const float*)d_in[16];
    const float* fcgw  = (const float*)d_in[17];
    const float* fcgb  = (const float*)d_in[18];
    const float* fccgw = (const float*)d_in[19];
    const float* fccgb = (const float*)d_in[20];

    // workspace layout — every offset a multiple of 64 floats (256 B)
    float* ws        = (float*)d_ws;
    float* dis       = ws;                            // 102400 fl
    int*   cnt       = (int*)(ws + 102400);           // 102400
    int*   starts    = cnt + 102400;                  // 102400
    int*   bkt_cur   = starts + 102400;               // 512
    int*   srclist   = bkt_cur + 512;                 // 2,002,048 (391*5120 rounded to 64)
    float* hbuf      = (float*)(srclist + 2002048);   // 6.4M fl: h2 bf16 [100k x 128]; pairs overlay
    float* c1f       = hbuf + 6400000;                // 3.2M fl: b1 bf16 [100k x 64] (256B-aligned)
    float* w1        = c1f + 3200000;                 // 3.2M fl
    float* c2f       = w1 + 3200000;                  // 1.6M fl: c2 bf16 [100k x 32]
    float* w2        = c2f + 1600000;                 // 3.2M fl
    unsigned short* wb = (unsigned short*)(w2 + 3200000);  // 28672 bf16 weights
    unsigned int*  pairs = (unsigned int*)hbuf;       // 8MB (<= 25.6MB region), dead before hb
    unsigned short* hb = (unsigned short*)hbuf;
    unsigned short* c1 = (unsigned short*)c1f;
    unsigned short* c2 = (unsigned short*)c2f;

    float* z_a  = (float*)d_out;
    float* z_c  = z_a + (size_t)N_GRAPHS * 64;
    float* hout = z_a + (size_t)2 * N_GRAPHS * 64;

    // setup: bucket cursors + weight bf16 conversion (57 blocks x 512)
    setup_k<<<57, 512, 0, stream>>>(bkt_cur, nfc_w, g1bw, g1cw, g2bw, g2cw, wb);
    // merged: binscatter (first; 98 fat blocks) || fusedA (x -> h1 -> b1,w1)
    scatterA_k<<<NBE + GBA, 256, 0, stream>>>(x, wb, nfc_b, g1cb, c1, w1, N_NODES,
                                              ei, bkt_cur, pairs);
    // bucket CSR: per-node starts/cnt/dis + srclist
    bucket_csr_k<<<NBKT, 256, 0, stream>>>(pairs, bkt_cur, starts, cnt, dis, srclist);
    // h2 = elu(dis_n * (W1 . (dis_n*b_n + sum dis_src*b_src)) + g1_bias) -> bf16 (hb)
    gather1_k<<<N_NODES / 4, 256, 0, stream>>>(starts, cnt, srclist, c1, w1, dis, g1b, hb);
    // fused: c2 = dis*(h2@g2bw^T) bf16 ; w2 = h2@g2cw^T + g2cb fp32
    mgemmL2_k<<<GBA, 256, 0, stream>>>(hb, wb, g2cb, dis, c2, w2, N_NODES);
    // fused: gather2 + L2 norm + per-graph pooling/attention heads
    graphfused_k<<<N_GRAPHS, 256, 0, stream>>>(starts, cnt, srclist, c2, w2, dis, g2b,
                                               z_e, aw, ab, fcgw, fcgb, fccgw, fccgb,
                                               hout, z_a, z_c);
}

// Round 18
// 235.776 us; speedup vs baseline: 1.4527x; 1.4527x over previous
//
#include <hip/hip_runtime.h>
#include <hip/hip_bf16.h>
#include <math.h>

#define N_NODES  100000
#define N_EDGES  1600000
#define N_GRAPHS 1000
#define NPG      100
#define NBKT     391          // ceil(100000/256); bucket = dst >> 8
#define BCAP     5120         // fixed bucket capacity (mean 4092, +16 sigma)
#define EPB      16384        // edges per block in binning (fat blocks: less bkt_cur contention)
#define NBE      ((N_EDGES + EPB - 1) / EPB)   // 98 edge blocks
#define GBA      ((N_NODES + 63) / 64)         // 1563 fusedA blocks

typedef float  f32x4 __attribute__((ext_vector_type(4)));
typedef short  s16x8 __attribute__((ext_vector_type(8)));

__device__ __forceinline__ float elu_f(float x) {
    return x > 0.0f ? x : expm1f(x);
}
__device__ __forceinline__ float bf2f(unsigned int u16) {
    union { unsigned int i; float f; } v; v.i = u16 << 16; return v.f;
}
__device__ __forceinline__ unsigned short f2bf(float f) {
    __hip_bfloat16 h = __float2bfloat16(f);
    return *reinterpret_cast<unsigned short*>(&h);
}
__device__ __forceinline__ s16x8 cvt8(const float4& a, const float4& b) {
    s16x8 o;
    o[0]=(short)f2bf(a.x); o[1]=(short)f2bf(a.y); o[2]=(short)f2bf(a.z); o[3]=(short)f2bf(a.w);
    o[4]=(short)f2bf(b.x); o[5]=(short)f2bf(b.y); o[6]=(short)f2bf(b.z); o[7]=(short)f2bf(b.w);
    return o;
}

// ---------------- setup: bucket cursors + weight bf16 conversion ----------------
__global__ __launch_bounds__(512) void setup_k(
    int* __restrict__ bkt_cur,
    const float* __restrict__ w0, const float* __restrict__ w1c, const float* __restrict__ w1w,
    const float* __restrict__ w2c, const float* __restrict__ w2w, unsigned short* __restrict__ wb)
{
    int t = threadIdx.x;
    if (blockIdx.x == 0 && t < NBKT) bkt_cur[t] = t * BCAP;
    int i = blockIdx.x * 512 + t;
    float v;
    if (i < 8192)       v = w0[i];
    else if (i < 16384) v = w1c[i - 8192];
    else if (i < 20480) v = w1w[i - 16384];
    else if (i < 24576) v = w2c[i - 20480];
    else if (i < 28672) v = w2w[i - 24576];
    else return;
    wb[i] = f2bf(v);
}

// ---------------- merged: binscatter (blocks [0,NBE)) || fusedA (blocks [NBE,NBE+GBA)) ----------------
__global__ __launch_bounds__(256) void scatterA_k(
    const float* __restrict__ x, const unsigned short* __restrict__ wb,
    const float* __restrict__ b0, const float* __restrict__ bw,
    unsigned short* __restrict__ c1out, float* __restrict__ w1out, int M,
    const int* __restrict__ ei, int* __restrict__ bkt_cur, unsigned int* __restrict__ pairs)
{
    __shared__ union {
        struct { int h[NBKT]; int base[NBKT]; } sc;
        unsigned short hT[64][136];
    } u;

    const int t = threadIdx.x;

    if (blockIdx.x < NBE) {
        // ---- binscatter branch (dispatched first; overlaps fusedA) ----
        const int eb = blockIdx.x;
        int* h = u.sc.h;
        int* base = u.sc.base;
        for (int i = t; i < NBKT; i += 256) h[i] = 0;
        __syncthreads();
        const int4* src4 = (const int4*)ei;
        const int4* dst4 = (const int4*)(ei + N_EDGES);
        int i0 = eb * (EPB / 4);
        for (int i = t; i < EPB / 4; i += 256) {
            int g = i0 + i;
            if (g < N_EDGES / 4) {
                int4 d = dst4[g];
                atomicAdd(&h[d.x >> 8], 1);
                atomicAdd(&h[d.y >> 8], 1);
                atomicAdd(&h[d.z >> 8], 1);
                atomicAdd(&h[d.w >> 8], 1);
            }
        }
        __syncthreads();
        for (int i = t; i < NBKT; i += 256) {
            int c = h[i];
            base[i] = c ? atomicAdd(&bkt_cur[i], c) : 0;
            h[i] = 0;
        }
        __syncthreads();
        for (int i = t; i < EPB / 4; i += 256) {
            int g = i0 + i;
            if (g < N_EDGES / 4) {
                int4 s4 = src4[g];
                int4 d4 = dst4[g];
                int b, r;
                b = d4.x >> 8; r = atomicAdd(&h[b], 1); pairs[base[b] + r] = ((unsigned)s4.x << 8) | (d4.x & 255);
                b = d4.y >> 8; r = atomicAdd(&h[b], 1); pairs[base[b] + r] = ((unsigned)s4.y << 8) | (d4.y & 255);
                b = d4.z >> 8; r = atomicAdd(&h[b], 1); pairs[base[b] + r] = ((unsigned)s4.z << 8) | (d4.z & 255);
                b = d4.w >> 8; r = atomicAdd(&h[b], 1); pairs[base[b] + r] = ((unsigned)s4.w << 8) | (d4.w & 255);
            }
        }
        return;
    }

    // ---- fusedA branch ----
    const unsigned short* W0b = wb;            // [128][64]
    const unsigned short* Wcb = wb + 8192;     // [64][128]
    const unsigned short* Wwb = wb + 16384;    // [32][128]

    const int wave = t >> 6, lane = t & 63;
    const int lr = lane & 15, lk = lane >> 4;
    const int blockRow = (blockIdx.x - NBE) * 64;

    // phase 1: h tile [64x128] = x[64x64] @ W0[128x64]^T
    {
        const int wr = wave >> 1, wc = wave & 1;
        f32x4 acc[2][4];
        #pragma unroll
        for (int rt = 0; rt < 2; ++rt)
            #pragma unroll
            for (int ct = 0; ct < 4; ++ct) acc[rt][ct] = (f32x4){0.f,0.f,0.f,0.f};

        #pragma unroll
        for (int kt = 0; kt < 2; ++kt) {
            const int k0 = kt * 32 + lk * 8;
            s16x8 afr[2];
            #pragma unroll
            for (int rt = 0; rt < 2; ++rt) {
                int r = blockRow + (wr * 2 + rt) * 16 + lr;
                r = (r < M) ? r : (M - 1);
                const float* ap = x + (size_t)r * 64 + k0;
                afr[rt] = cvt8(*(const float4*)ap, *(const float4*)(ap + 4));
            }
            s16x8 bfr[4];
            #pragma unroll
            for (int ct = 0; ct < 4; ++ct) {
                int n = (wc * 4 + ct) * 16 + lr;
                bfr[ct] = *(const s16x8*)(W0b + (size_t)n * 64 + k0);
            }
            #pragma unroll
            for (int rt = 0; rt < 2; ++rt)
                #pragma unroll
                for (int ct = 0; ct < 4; ++ct)
                    acc[rt][ct] = __builtin_amdgcn_mfma_f32_16x16x32_bf16(afr[rt], bfr[ct], acc[rt][ct], 0, 0, 0);
        }
        #pragma unroll
        for (int rt = 0; rt < 2; ++rt) {
            int lmb = (wr * 2 + rt) * 16 + lk * 4;
            #pragma unroll
            for (int j = 0; j < 4; ++j) {
                #pragma unroll
                for (int ct = 0; ct < 4; ++ct) {
                    int n = (wc * 4 + ct) * 16 + lr;
                    u.hT[lmb + j][n] = f2bf(elu_f(acc[rt][ct][j] + b0[n]));
                }
            }
        }
    }
    __syncthreads();

    // phase 2: [64x128] @ [96x128]^T ; cols 0..63 -> b1 (unscaled), 64..95 -> w1
    {
        f32x4 acc[6];
        #pragma unroll
        for (int ct = 0; ct < 6; ++ct) acc[ct] = (f32x4){0.f,0.f,0.f,0.f};
        #pragma unroll
        for (int kt = 0; kt < 4; ++kt) {
            const int k0 = kt * 32 + lk * 8;
            s16x8 af = *(const s16x8*)&u.hT[wave * 16 + lr][k0];
            #pragma unroll
            for (int ct = 0; ct < 6; ++ct) {
                int n = ct * 16 + lr;
                const unsigned short* wp = (n < 64) ? (Wcb + (size_t)n * 128 + k0)
                                                    : (Wwb + (size_t)(n - 64) * 128 + k0);
                acc[ct] = __builtin_amdgcn_mfma_f32_16x16x32_bf16(af, *(const s16x8*)wp, acc[ct], 0, 0, 0);
            }
        }
        int mbase = blockRow + wave * 16 + lk * 4;
        #pragma unroll
        for (int j = 0; j < 4; ++j) {
            int m = mbase + j;
            if (m >= M) continue;
            #pragma unroll
            for (int ct = 0; ct < 6; ++ct) {
                int n = ct * 16 + lr;
                float v = acc[ct][j];
                if (n < 64) c1out[(size_t)m * 64 + n] = f2bf(v);
                else        w1out[(size_t)m * 32 + (n - 64)] = v + bw[n - 64];
            }
        }
    }
}

// ---------------- bucket CSR: per-node counts/starts/dis + srclist ----------------
__global__ __launch_bounds__(256) void bucket_csr_k(const unsigned int* __restrict__ pairs,
                                                    const int* __restrict__ bkt_cur,
                                                    int* __restrict__ starts,
                                                    int* __restrict__ cnt,
                                                    float* __restrict__ dis,
                                                    int* __restrict__ srclist)
{
    __shared__ int s[256];
    __shared__ int cur[256];
    const int b = blockIdx.x, t = threadIdx.x;
    const int lo = b * BCAP;
    const int hi = bkt_cur[b];
    const int n0 = b << 8;
    const int nn = min(256, N_NODES - n0);

    s[t] = 0;
    __syncthreads();
    for (int i = lo + t; i < hi; i += 256) {
        unsigned int p = pairs[i];
        atomicAdd(&s[p & 255], 1);
    }
    __syncthreads();
    int v = s[t];
    __syncthreads();
    s[t] = v;
    __syncthreads();
    #pragma unroll
    for (int off = 1; off < 256; off <<= 1) {
        int u = (t >= off) ? s[t - off] : 0;
        __syncthreads();
        s[t] += u;
        __syncthreads();
    }
    int ex = lo + s[t] - v;
    if (t < nn) {
        starts[n0 + t] = ex;
        cnt[n0 + t] = v;
        dis[n0 + t] = rsqrtf(1.0f + (float)v);
    }
    cur[t] = ex;
    __syncthreads();
    for (int i = lo + t; i < hi; i += 256) {
        unsigned int p = pairs[i];
        int pos = atomicAdd(&cur[p & 255], 1);
        srclist[pos] = (int)(p >> 8);
    }
}

// ---------------- layer-2 fused GEMM: c2 = dis*(h2@Wc^T) bf16 ; w2 = h2@Ww^T+bw fp32 ----------------
__global__ __launch_bounds__(256) void mgemmL2_k(
    const unsigned short* __restrict__ Ab, const unsigned short* __restrict__ wb,
    const float* __restrict__ bw, const float* __restrict__ dis,
    unsigned short* __restrict__ c2out, float* __restrict__ w2out, int M)
{
    const unsigned short* Wcb = wb + 20480;    // [32][128]
    const unsigned short* Wwb = wb + 24576;    // [32][128]

    const int t = threadIdx.x;
    const int wave = t >> 6, lane = t & 63;
    const int wr = wave >> 1, wc = wave & 1;
    const int lr = lane & 15, lk = lane >> 4;
    const int blockRow = blockIdx.x * 64;

    f32x4 acc[2][2];
    #pragma unroll
    for (int rt = 0; rt < 2; ++rt)
        #pragma unroll
        for (int ct = 0; ct < 2; ++ct) acc[rt][ct] = (f32x4){0.f,0.f,0.f,0.f};

    #pragma unroll
    for (int kt = 0; kt < 4; ++kt) {
        const int k0 = kt * 32 + lk * 8;
        s16x8 afr[2];
        #pragma unroll
        for (int rt = 0; rt < 2; ++rt) {
            int r = blockRow + (wr * 2 + rt) * 16 + lr;
            r = (r < M) ? r : (M - 1);
            afr[rt] = *(const s16x8*)(Ab + (size_t)r * 128 + k0);
        }
        s16x8 bfr[2];
        #pragma unroll
        for (int ct = 0; ct < 2; ++ct) {
            int n = (wc * 2 + ct) * 16 + lr;
            const unsigned short* wp = (n < 32) ? (Wcb + (size_t)n * 128 + k0)
                                                : (Wwb + (size_t)(n - 32) * 128 + k0);
            bfr[ct] = *(const s16x8*)wp;
        }
        #pragma unroll
        for (int rt = 0; rt < 2; ++rt)
            #pragma unroll
            for (int ct = 0; ct < 2; ++ct)
                acc[rt][ct] = __builtin_amdgcn_mfma_f32_16x16x32_bf16(afr[rt], bfr[ct], acc[rt][ct], 0, 0, 0);
    }

    #pragma unroll
    for (int rt = 0; rt < 2; ++rt) {
        int mbase = blockRow + (wr * 2 + rt) * 16 + lk * 4;
        #pragma unroll
        for (int j = 0; j < 4; ++j) {
            int m = mbase + j;
            if (m >= M) continue;
            float dsc = dis[m];
            #pragma unroll
            for (int ct = 0; ct < 2; ++ct) {
                int n = (wc * 2 + ct) * 16 + lr;
                float v = acc[rt][ct][j];
                if (n < 32) c2out[(size_t)m * 32 + n] = f2bf(dsc * v);
                else        w2out[(size_t)m * 32 + (n - 32)] = v + bw[n - 32];
            }
        }
    }
}

// ---------------- layer-1 gather (wave/node, 4 edge slots) + combine + elu ----------------
__global__ __launch_bounds__(256) void gather1_k(
    const int* __restrict__ starts, const int* __restrict__ cnt,
    const int* __restrict__ srclist, const unsigned short* __restrict__ c,
    const float* __restrict__ w1, const float* __restrict__ dis,
    const float* __restrict__ bias, unsigned short* __restrict__ h2b)
{
    __shared__ float aggS[4][68];

    const int t = threadIdx.x;
    const int nn   = t >> 6;
    const int lane = t & 63;
    const int q    = lane & 15;
    const int slot = lane >> 4;
    const int n    = blockIdx.x * 4 + nn;

    const int s0 = starts[n];
    const int cn = cnt[n];
    float a0 = 0.f, a1 = 0.f, a2 = 0.f, a3 = 0.f;
    if (slot == 0) {                                    // self term: dis[n]*b[n]
        float dsn = dis[n];
        uint2 u = *(const uint2*)(c + (size_t)n * 64 + q * 4);
        a0 = dsn * bf2f(u.x & 0xffff); a1 = dsn * bf2f(u.x >> 16);
        a2 = dsn * bf2f(u.y & 0xffff); a3 = dsn * bf2f(u.y >> 16);
    }
    for (int j = slot; j < cn; j += 4) {
        int src = srclist[s0 + j];
        float ds = dis[src];
        uint2 u = *(const uint2*)(c + (size_t)src * 64 + q * 4);
        a0 = fmaf(ds, bf2f(u.x & 0xffff), a0); a1 = fmaf(ds, bf2f(u.x >> 16), a1);
        a2 = fmaf(ds, bf2f(u.y & 0xffff), a2); a3 = fmaf(ds, bf2f(u.y >> 16), a3);
    }
    a0 += __shfl_xor(a0, 16, 64); a0 += __shfl_xor(a0, 32, 64);
    a1 += __shfl_xor(a1, 16, 64); a1 += __shfl_xor(a1, 32, 64);
    a2 += __shfl_xor(a2, 16, 64); a2 += __shfl_xor(a2, 32, 64);
    a3 += __shfl_xor(a3, 16, 64); a3 += __shfl_xor(a3, 32, 64);
    if (slot == 0) {
        aggS[nn][q * 4 + 0] = a0;
        aggS[nn][q * 4 + 1] = a1;
        aggS[nn][q * 4 + 2] = a2;
        aggS[nn][q * 4 + 3] = a3;
    }
    __syncthreads();

    const float dn = dis[n];
    const float* wr = w1 + (size_t)n * 32;
    unsigned short* out = h2b + (size_t)n * 128;
    #pragma unroll
    for (int r = 0; r < 2; ++r) {
        int j = r * 64 + lane;
        int hh = j >> 4, f = j & 15;
        float4 wv = *(const float4*)(wr + hh * 4);
        float s = wv.x * aggS[nn][0 * 16 + f] + wv.y * aggS[nn][1 * 16 + f]
                + wv.z * aggS[nn][2 * 16 + f] + wv.w * aggS[nn][3 * 16 + f];
        out[j] = f2bf(elu_f(s * dn + bias[j]));
    }
}

// ---------------- layer-2 gather (wave/node, 4 edge slots) + combine + elu + L2 norm ----------------
__global__ __launch_bounds__(256) void gather2_k(
    const int* __restrict__ starts, const int* __restrict__ cnt,
    const int* __restrict__ srclist, const unsigned short* __restrict__ c,
    const float* __restrict__ w2, const float* __restrict__ dis,
    const float* __restrict__ bias, float* __restrict__ hout)
{
    __shared__ float aggS[4][36];

    const int t = threadIdx.x;
    const int nn   = t >> 6;
    const int lane = t & 63;
    const int q    = lane & 15;
    const int slot = lane >> 4;
    const int n    = blockIdx.x * 4 + nn;

    const int s0 = starts[n];
    const int cn = cnt[n];
    float a0 = 0.f, a1 = 0.f;
    if (slot == 0) {
        unsigned int u = *(const unsigned int*)(c + (size_t)n * 32 + q * 2);
        a0 = bf2f(u & 0xffff); a1 = bf2f(u >> 16);
    }
    for (int j = slot; j < cn; j += 4) {
        int src = srclist[s0 + j];
        unsigned int u = *(const unsigned int*)(c + (size_t)src * 32 + q * 2);
        a0 += bf2f(u & 0xffff); a1 += bf2f(u >> 16);
    }
    a0 += __shfl_xor(a0, 16, 64); a0 += __shfl_xor(a0, 32, 64);
    a1 += __shfl_xor(a1, 16, 64); a1 += __shfl_xor(a1, 32, 64);
    if (slot == 0) {
        aggS[nn][q * 2 + 0] = a0;
        aggS[nn][q * 2 + 1] = a1;
    }
    __syncthreads();

    const float dn = dis[n];
    const int hh = lane >> 3, f = lane & 7;
    float4 wv = *(const float4*)(w2 + (size_t)n * 32 + hh * 4);
    float s = wv.x * aggS[nn][0 * 8 + f] + wv.y * aggS[nn][1 * 8 + f]
            + wv.z * aggS[nn][2 * 8 + f] + wv.w * aggS[nn][3 * 8 + f];
    float sv = elu_f(s * dn + bias[lane]);

    float tot = sv * sv;
    #pragma unroll
    for (int o = 1; o < 64; o <<= 1) tot += __shfl_xor(tot, o, 64);
    float inv = 1.0f / fmaxf(sqrtf(tot), 1e-12f);
    hout[(size_t)n * 64 + lane] = sv * inv;
}

// ---------------- per-graph tail: z_a, attention softmax, z_c ----------------
__global__ __launch_bounds__(128) void graph_k(const float* __restrict__ h,
                                               const float* __restrict__ z_e,
                                               const float* __restrict__ aw,
                                               const float* __restrict__ ab,
                                               const float* __restrict__ fcgw,
                                               const float* __restrict__ fcgb,
                                               const float* __restrict__ fccgw,
                                               const float* __restrict__ fccgb,
                                               float* __restrict__ z_a,
                                               float* __restrict__ z_c)
{
    __shared__ float Hs[NPG * 64];
    __shared__ float sumh[64], wsh[64], lg[NPG], ex[NPG];
    __shared__ float red[2];
    int g = blockIdx.x, t = threadIdx.x;
    const float* hg = h + (size_t)g * NPG * 64;
    for (int idx = t; idx < NPG * 64; idx += 128) Hs[idx] = hg[idx];
    __syncthreads();

    if (t < 64) {
        float s = 0.0f;
        for (int n = 0; n < NPG; ++n) s += Hs[n * 64 + t];
        sumh[t] = s;
    }
    __syncthreads();

    if (t < 64) {
        float acc = fcgb[t];
        for (int f = 0; f < 64; ++f) acc = fmaf(sumh[f], fcgw[t * 64 + f], acc);
        z_a[(size_t)g * 64 + t] = acc;
    }
    if (t < NPG) {
        float zd = 0.0f;
        for (int q = 0; q < 32; ++q) zd = fmaf(z_e[(size_t)g * 32 + q], aw[64 + q], zd);
        float dot = 0.0f;
        for (int k0 = 0; k0 < 64; ++k0) {
            int k = (k0 + t) & 63;
            dot = fmaf(Hs[t * 64 + k], aw[k], dot);
        }
        lg[t] = dot + zd + ab[0] + 1e-16f;
    }
    __syncthreads();

    if (t < 64) {
        float m = -INFINITY;
        for (int n = t; n < NPG; n += 64) m = fmaxf(m, lg[n]);
        #pragma unroll
        for (int o = 1; o < 64; o <<= 1) m = fmaxf(m, __shfl_xor(m, o, 64));
        if (t == 0) red[0] = m;
    }
    __syncthreads();
    float m = red[0];
    if (t < NPG) ex[t] = expf(lg[t] - m);
    __syncthreads();
    if (t < 64) {
        float s = 0.0f;
        for (int n = t; n < NPG; n += 64) s += ex[n];
        #pragma unroll
        for (int o = 1; o < 64; o <<= 1) s += __shfl_xor(s, o, 64);
        if (t == 0) red[1] = s + 1e-16f;
    }
    __syncthreads();
    float inv_denom = 1.0f / red[1];
    if (t < 64) {
        float a = 0.0f;
        for (int n = 0; n < NPG; ++n) a = fmaf(ex[n], Hs[n * 64 + t], a);
        wsh[t] = a * inv_denom;
    }
    __syncthreads();
    if (t < 64) {
        float acc = fccgb[t];
        for (int f = 0; f < 64; ++f) acc = fmaf(wsh[f], fccgw[t * 64 + f], acc);
        z_c[(size_t)g * 64 + t] = acc;
    }
}

extern "C" void kernel_launch(void* const* d_in, const int* in_sizes, int n_in,
                              void* d_out, int out_size, void* d_ws, size_t ws_size,
                              hipStream_t stream)
{
    const float* x     = (const float*)d_in[0];
    const int*   ei    = (const int*)d_in[1];
    const float* z_e   = (const float*)d_in[4];
    const float* nfc_w = (const float*)d_in[5];
    const float* nfc_b = (const float*)d_in[6];
    const float* g1bw  = (const float*)d_in[7];
    const float* g1cw  = (const float*)d_in[8];
    const float* g1cb  = (const float*)d_in[9];
    const float* g1b   = (const float*)d_in[10];
    const float* g2bw  = (const float*)d_in[11];
    const float* g2cw  = (const float*)d_in[12];
    const float* g2cb  = (const float*)d_in[13];
    const float* g2b   = (const float*)d_in[14];
    const float* aw    = (const float*)d_in[15];
    const float* ab    = (const float*)d_in[16];
    const float* fcgw  = (const float*)d_in[17];
    const float* fcgb  = (const float*)d_in[18];
    const float* fccgw = (const float*)d_in[19];
    const float* fccgb = (const float*)d_in[20];

    // workspace layout — every offset a multiple of 64 floats (256 B)
    float* ws        = (float*)d_ws;
    float* dis       = ws;                            // 102400 fl
    int*   cnt       = (int*)(ws + 102400);           // 102400
    int*   starts    = cnt + 102400;                  // 102400
    int*   bkt_cur   = starts + 102400;               // 512
    int*   srclist   = bkt_cur + 512;                 // 2,002,048 (391*5120 rounded to 64)
    float* hbuf      = (float*)(srclist + 2002048);   // 6.4M fl: h2 bf16 [100k x 128]; pairs overlay
    float* c1f       = hbuf + 6400000;                // 3.2M fl: b1 bf16 [100k x 64] (256B-aligned)
    float* w1        = c1f + 3200000;                 // 3.2M fl
    float* c2f       = w1 + 3200000;                  // 1.6M fl: c2 bf16 [100k x 32]
    float* w2        = c2f + 1600000;                 // 3.2M fl
    unsigned short* wb = (unsigned short*)(w2 + 3200000);  // 28672 bf16 weights
    unsigned int*  pairs = (unsigned int*)hbuf;       // 8MB (<= 25.6MB region), dead before hb
    unsigned short* hb = (unsigned short*)hbuf;
    unsigned short* c1 = (unsigned short*)c1f;
    unsigned short* c2 = (unsigned short*)c2f;

    float* z_a  = (float*)d_out;
    float* z_c  = z_a + (size_t)N_GRAPHS * 64;
    float* hout = z_a + (size_t)2 * N_GRAPHS * 64;

    // setup: bucket cursors + weight bf16 conversion (57 blocks x 512)
    setup_k<<<57, 512, 0, stream>>>(bkt_cur, nfc_w, g1bw, g1cw, g2bw, g2cw, wb);
    // merged: binscatter (first; 98 fat blocks) || fusedA (x -> h1 -> b1,w1)
    scatterA_k<<<NBE + GBA, 256, 0, stream>>>(x, wb, nfc_b, g1cb, c1, w1, N_NODES,
                                              ei, bkt_cur, pairs);
    // bucket CSR: per-node starts/cnt/dis + srclist
    bucket_csr_k<<<NBKT, 256, 0, stream>>>(pairs, bkt_cur, starts, cnt, dis, srclist);
    // h2 = elu(dis_n * (W1 . (dis_n*b_n + sum dis_src*b_src)) + g1_bias) -> bf16 (hb)
    gather1_k<<<N_NODES / 4, 256, 0, stream>>>(starts, cnt, srclist, c1, w1, dis, g1b, hb);
    // fused: c2 = dis*(h2@g2bw^T) bf16 ; w2 = h2@g2cw^T + g2cb fp32
    mgemmL2_k<<<GBA, 256, 0, stream>>>(hb, wb, g2cb, dis, c2, w2, N_NODES);
    // h = normalize(elu(dis * combine(w2, gather(c2)) + g2_bias))
    gather2_k<<<N_NODES / 4, 256, 0, stream>>>(starts, cnt, srclist, c2, w2, dis, g2b, hout);
    // per-graph pooling + attention heads
    graph_k<<<N_GRAPHS, 128, 0, stream>>>(hout, z_e, aw, ab, fcgw, fcgb, fccgw, fccgb, z_a, z_c);
}

// Round 19
// 235.543 us; speedup vs baseline: 1.4541x; 1.0010x over previous
//
#include <hip/hip_runtime.h>
#include <hip/hip_bf16.h>
#include <math.h>

#define N_NODES  100000
#define N_EDGES  1600000
#define N_GRAPHS 1000
#define NPG      100
#define NBKT     391          // ceil(100000/256); bucket = dst >> 8
#define BCAP     5120         // fixed bucket capacity (mean 4092, +16 sigma)
#define EPB      16384        // edges per block in binning (fat blocks: less bkt_cur contention)
#define NBE      ((N_EDGES + EPB - 1) / EPB)   // 98 edge blocks
#define GBA      ((N_NODES + 63) / 64)         // 1563 fusedA blocks

typedef float  f32x4 __attribute__((ext_vector_type(4)));
typedef short  s16x8 __attribute__((ext_vector_type(8)));

__device__ __forceinline__ float elu_f(float x) {
    return x > 0.0f ? x : expm1f(x);
}
__device__ __forceinline__ float bf2f(unsigned int u16) {
    union { unsigned int i; float f; } v; v.i = u16 << 16; return v.f;
}
__device__ __forceinline__ unsigned short f2bf(float f) {
    __hip_bfloat16 h = __float2bfloat16(f);
    return *reinterpret_cast<unsigned short*>(&h);
}
__device__ __forceinline__ s16x8 cvt8(const float4& a, const float4& b) {
    s16x8 o;
    o[0]=(short)f2bf(a.x); o[1]=(short)f2bf(a.y); o[2]=(short)f2bf(a.z); o[3]=(short)f2bf(a.w);
    o[4]=(short)f2bf(b.x); o[5]=(short)f2bf(b.y); o[6]=(short)f2bf(b.z); o[7]=(short)f2bf(b.w);
    return o;
}

// ---------------- setup: bucket cursors + weight bf16 conversion ----------------
__global__ __launch_bounds__(512) void setup_k(
    int* __restrict__ bkt_cur,
    const float* __restrict__ w0, const float* __restrict__ w1c, const float* __restrict__ w1w,
    const float* __restrict__ w2c, const float* __restrict__ w2w, unsigned short* __restrict__ wb)
{
    int t = threadIdx.x;
    if (blockIdx.x == 0 && t < NBKT) bkt_cur[t] = t * BCAP;
    int i = blockIdx.x * 512 + t;
    float v;
    if (i < 8192)       v = w0[i];
    else if (i < 16384) v = w1c[i - 8192];
    else if (i < 20480) v = w1w[i - 16384];
    else if (i < 24576) v = w2c[i - 20480];
    else if (i < 28672) v = w2w[i - 24576];
    else return;
    wb[i] = f2bf(v);
}

// ---------------- merged: binscatter (blocks [0,NBE)) || fusedA (blocks [NBE,NBE+GBA)) ----------------
__global__ __launch_bounds__(256) void scatterA_k(
    const float* __restrict__ x, const unsigned short* __restrict__ wb,
    const float* __restrict__ b0, const float* __restrict__ bw,
    unsigned short* __restrict__ c1out, float* __restrict__ w1out, int M,
    const int* __restrict__ ei, int* __restrict__ bkt_cur, unsigned int* __restrict__ pairs)
{
    __shared__ union {
        struct { int h[NBKT]; int base[NBKT]; } sc;
        unsigned short hT[64][136];
    } u;

    const int t = threadIdx.x;

    if (blockIdx.x < NBE) {
        // ---- binscatter branch (dispatched first; overlaps fusedA) ----
        const int eb = blockIdx.x;
        int* h = u.sc.h;
        int* base = u.sc.base;
        for (int i = t; i < NBKT; i += 256) h[i] = 0;
        __syncthreads();
        const int4* src4 = (const int4*)ei;
        const int4* dst4 = (const int4*)(ei + N_EDGES);
        int i0 = eb * (EPB / 4);
        for (int i = t; i < EPB / 4; i += 256) {
            int g = i0 + i;
            if (g < N_EDGES / 4) {
                int4 d = dst4[g];
                atomicAdd(&h[d.x >> 8], 1);
                atomicAdd(&h[d.y >> 8], 1);
                atomicAdd(&h[d.z >> 8], 1);
                atomicAdd(&h[d.w >> 8], 1);
            }
        }
        __syncthreads();
        for (int i = t; i < NBKT; i += 256) {
            int c = h[i];
            base[i] = c ? atomicAdd(&bkt_cur[i], c) : 0;
            h[i] = 0;
        }
        __syncthreads();
        for (int i = t; i < EPB / 4; i += 256) {
            int g = i0 + i;
            if (g < N_EDGES / 4) {
                int4 s4 = src4[g];
                int4 d4 = dst4[g];
                int b, r;
                b = d4.x >> 8; r = atomicAdd(&h[b], 1); pairs[base[b] + r] = ((unsigned)s4.x << 8) | (d4.x & 255);
                b = d4.y >> 8; r = atomicAdd(&h[b], 1); pairs[base[b] + r] = ((unsigned)s4.y << 8) | (d4.y & 255);
                b = d4.z >> 8; r = atomicAdd(&h[b], 1); pairs[base[b] + r] = ((unsigned)s4.z << 8) | (d4.z & 255);
                b = d4.w >> 8; r = atomicAdd(&h[b], 1); pairs[base[b] + r] = ((unsigned)s4.w << 8) | (d4.w & 255);
            }
        }
        return;
    }

    // ---- fusedA branch ----
    const unsigned short* W0b = wb;            // [128][64]
    const unsigned short* Wcb = wb + 8192;     // [64][128]
    const unsigned short* Wwb = wb + 16384;    // [32][128]

    const int wave = t >> 6, lane = t & 63;
    const int lr = lane & 15, lk = lane >> 4;
    const int blockRow = (blockIdx.x - NBE) * 64;

    // phase 1: h tile [64x128] = x[64x64] @ W0[128x64]^T
    {
        const int wr = wave >> 1, wc = wave & 1;
        f32x4 acc[2][4];
        #pragma unroll
        for (int rt = 0; rt < 2; ++rt)
            #pragma unroll
            for (int ct = 0; ct < 4; ++ct) acc[rt][ct] = (f32x4){0.f,0.f,0.f,0.f};

        #pragma unroll
        for (int kt = 0; kt < 2; ++kt) {
            const int k0 = kt * 32 + lk * 8;
            s16x8 afr[2];
            #pragma unroll
            for (int rt = 0; rt < 2; ++rt) {
                int r = blockRow + (wr * 2 + rt) * 16 + lr;
                r = (r < M) ? r : (M - 1);
                const float* ap = x + (size_t)r * 64 + k0;
                afr[rt] = cvt8(*(const float4*)ap, *(const float4*)(ap + 4));
            }
            s16x8 bfr[4];
            #pragma unroll
            for (int ct = 0; ct < 4; ++ct) {
                int n = (wc * 4 + ct) * 16 + lr;
                bfr[ct] = *(const s16x8*)(W0b + (size_t)n * 64 + k0);
            }
            #pragma unroll
            for (int rt = 0; rt < 2; ++rt)
                #pragma unroll
                for (int ct = 0; ct < 4; ++ct)
                    acc[rt][ct] = __builtin_amdgcn_mfma_f32_16x16x32_bf16(afr[rt], bfr[ct], acc[rt][ct], 0, 0, 0);
        }
        #pragma unroll
        for (int rt = 0; rt < 2; ++rt) {
            int lmb = (wr * 2 + rt) * 16 + lk * 4;
            #pragma unroll
            for (int j = 0; j < 4; ++j) {
                #pragma unroll
                for (int ct = 0; ct < 4; ++ct) {
                    int n = (wc * 4 + ct) * 16 + lr;
                    u.hT[lmb + j][n] = f2bf(elu_f(acc[rt][ct][j] + b0[n]));
                }
            }
        }
    }
    __syncthreads();

    // phase 2: [64x128] @ [96x128]^T ; cols 0..63 -> b1 (unscaled), 64..95 -> w1
    {
        f32x4 acc[6];
        #pragma unroll
        for (int ct = 0; ct < 6; ++ct) acc[ct] = (f32x4){0.f,0.f,0.f,0.f};
        #pragma unroll
        for (int kt = 0; kt < 4; ++kt) {
            const int k0 = kt * 32 + lk * 8;
            s16x8 af = *(const s16x8*)&u.hT[wave * 16 + lr][k0];
            #pragma unroll
            for (int ct = 0; ct < 6; ++ct) {
                int n = ct * 16 + lr;
                const unsigned short* wp = (n < 64) ? (Wcb + (size_t)n * 128 + k0)
                                                    : (Wwb + (size_t)(n - 64) * 128 + k0);
                acc[ct] = __builtin_amdgcn_mfma_f32_16x16x32_bf16(af, *(const s16x8*)wp, acc[ct], 0, 0, 0);
            }
        }
        int mbase = blockRow + wave * 16 + lk * 4;
        #pragma unroll
        for (int j = 0; j < 4; ++j) {
            int m = mbase + j;
            if (m >= M) continue;
            #pragma unroll
            for (int ct = 0; ct < 6; ++ct) {
                int n = ct * 16 + lr;
                float v = acc[ct][j];
                if (n < 64) c1out[(size_t)m * 64 + n] = f2bf(v);
                else        w1out[(size_t)m * 32 + (n - 64)] = v + bw[n - 64];
            }
        }
    }
}

// ---------------- bucket CSR: per-node counts/starts/dis + srclist ----------------
__global__ __launch_bounds__(256) void bucket_csr_k(const unsigned int* __restrict__ pairs,
                                                    const int* __restrict__ bkt_cur,
                                                    int* __restrict__ starts,
                                                    int* __restrict__ cnt,
                                                    float* __restrict__ dis,
                                                    int* __restrict__ srclist)
{
    __shared__ int s[256];
    __shared__ int cur[256];
    const int b = blockIdx.x, t = threadIdx.x;
    const int lo = b * BCAP;
    const int hi = bkt_cur[b];
    const int n0 = b << 8;
    const int nn = min(256, N_NODES - n0);

    s[t] = 0;
    __syncthreads();
    for (int i = lo + t; i < hi; i += 256) {
        unsigned int p = pairs[i];
        atomicAdd(&s[p & 255], 1);
    }
    __syncthreads();
    int v = s[t];
    __syncthreads();
    s[t] = v;
    __syncthreads();
    #pragma unroll
    for (int off = 1; off < 256; off <<= 1) {
        int u = (t >= off) ? s[t - off] : 0;
        __syncthreads();
        s[t] += u;
        __syncthreads();
    }
    int ex = lo + s[t] - v;
    if (t < nn) {
        starts[n0 + t] = ex;
        cnt[n0 + t] = v;
        dis[n0 + t] = rsqrtf(1.0f + (float)v);
    }
    cur[t] = ex;
    __syncthreads();
    for (int i = lo + t; i < hi; i += 256) {
        unsigned int p = pairs[i];
        int pos = atomicAdd(&cur[p & 255], 1);
        srclist[pos] = (int)(p >> 8);
    }
}

// ---------------- layer-2 fused GEMM: c2 = dis*(h2@Wc^T) bf16 ; w2 = h2@Ww^T+bw fp32 ----------------
__global__ __launch_bounds__(256) void mgemmL2_k(
    const unsigned short* __restrict__ Ab, const unsigned short* __restrict__ wb,
    const float* __restrict__ bw, const float* __restrict__ dis,
    unsigned short* __restrict__ c2out, float* __restrict__ w2out, int M)
{
    const unsigned short* Wcb = wb + 20480;    // [32][128]
    const unsigned short* Wwb = wb + 24576;    // [32][128]

    const int t = threadIdx.x;
    const int wave = t >> 6, lane = t & 63;
    const int wr = wave >> 1, wc = wave & 1;
    const int lr = lane & 15, lk = lane >> 4;
    const int blockRow = blockIdx.x * 64;

    f32x4 acc[2][2];
    #pragma unroll
    for (int rt = 0; rt < 2; ++rt)
        #pragma unroll
        for (int ct = 0; ct < 2; ++ct) acc[rt][ct] = (f32x4){0.f,0.f,0.f,0.f};

    #pragma unroll
    for (int kt = 0; kt < 4; ++kt) {
        const int k0 = kt * 32 + lk * 8;
        s16x8 afr[2];
        #pragma unroll
        for (int rt = 0; rt < 2; ++rt) {
            int r = blockRow + (wr * 2 + rt) * 16 + lr;
            r = (r < M) ? r : (M - 1);
            afr[rt] = *(const s16x8*)(Ab + (size_t)r * 128 + k0);
        }
        s16x8 bfr[2];
        #pragma unroll
        for (int ct = 0; ct < 2; ++ct) {
            int n = (wc * 2 + ct) * 16 + lr;
            const unsigned short* wp = (n < 32) ? (Wcb + (size_t)n * 128 + k0)
                                                : (Wwb + (size_t)(n - 32) * 128 + k0);
            bfr[ct] = *(const s16x8*)wp;
        }
        #pragma unroll
        for (int rt = 0; rt < 2; ++rt)
            #pragma unroll
            for (int ct = 0; ct < 2; ++ct)
                acc[rt][ct] = __builtin_amdgcn_mfma_f32_16x16x32_bf16(afr[rt], bfr[ct], acc[rt][ct], 0, 0, 0);
    }

    #pragma unroll
    for (int rt = 0; rt < 2; ++rt) {
        int mbase = blockRow + (wr * 2 + rt) * 16 + lk * 4;
        #pragma unroll
        for (int j = 0; j < 4; ++j) {
            int m = mbase + j;
            if (m >= M) continue;
            float dsc = dis[m];
            #pragma unroll
            for (int ct = 0; ct < 2; ++ct) {
                int n = (wc * 2 + ct) * 16 + lr;
                float v = acc[rt][ct][j];
                if (n < 32) c2out[(size_t)m * 32 + n] = f2bf(dsc * v);
                else        w2out[(size_t)m * 32 + (n - 32)] = v + bw[n - 32];
            }
        }
    }
}

// ---------------- layer-1 gather (wave/node, 4 edge slots) + combine + elu ----------------
__global__ __launch_bounds__(256) void gather1_k(
    const int* __restrict__ starts, const int* __restrict__ cnt,
    const int* __restrict__ srclist, const unsigned short* __restrict__ c,
    const float* __restrict__ w1, const float* __restrict__ dis,
    const float* __restrict__ bias, unsigned short* __restrict__ h2b)
{
    __shared__ float aggS[4][68];

    const int t = threadIdx.x;
    const int nn   = t >> 6;
    const int lane = t & 63;
    const int q    = lane & 15;
    const int slot = lane >> 4;
    const int n    = blockIdx.x * 4 + nn;

    const int s0 = starts[n];
    const int cn = cnt[n];
    float a0 = 0.f, a1 = 0.f, a2 = 0.f, a3 = 0.f;
    if (slot == 0) {                                    // self term: dis[n]*b[n]
        float dsn = dis[n];
        uint2 u = *(const uint2*)(c + (size_t)n * 64 + q * 4);
        a0 = dsn * bf2f(u.x & 0xffff); a1 = dsn * bf2f(u.x >> 16);
        a2 = dsn * bf2f(u.y & 0xffff); a3 = dsn * bf2f(u.y >> 16);
    }
    for (int j = slot; j < cn; j += 4) {
        int src = srclist[s0 + j];
        float ds = dis[src];
        uint2 u = *(const uint2*)(c + (size_t)src * 64 + q * 4);
        a0 = fmaf(ds, bf2f(u.x & 0xffff), a0); a1 = fmaf(ds, bf2f(u.x >> 16), a1);
        a2 = fmaf(ds, bf2f(u.y & 0xffff), a2); a3 = fmaf(ds, bf2f(u.y >> 16), a3);
    }
    a0 += __shfl_xor(a0, 16, 64); a0 += __shfl_xor(a0, 32, 64);
    a1 += __shfl_xor(a1, 16, 64); a1 += __shfl_xor(a1, 32, 64);
    a2 += __shfl_xor(a2, 16, 64); a2 += __shfl_xor(a2, 32, 64);
    a3 += __shfl_xor(a3, 16, 64); a3 += __shfl_xor(a3, 32, 64);
    if (slot == 0) {
        aggS[nn][q * 4 + 0] = a0;
        aggS[nn][q * 4 + 1] = a1;
        aggS[nn][q * 4 + 2] = a2;
        aggS[nn][q * 4 + 3] = a3;
    }
    __syncthreads();

    const float dn = dis[n];
    const float* wr = w1 + (size_t)n * 32;
    unsigned short* out = h2b + (size_t)n * 128;
    #pragma unroll
    for (int r = 0; r < 2; ++r) {
        int j = r * 64 + lane;
        int hh = j >> 4, f = j & 15;
        float4 wv = *(const float4*)(wr + hh * 4);
        float s = wv.x * aggS[nn][0 * 16 + f] + wv.y * aggS[nn][1 * 16 + f]
                + wv.z * aggS[nn][2 * 16 + f] + wv.w * aggS[nn][3 * 16 + f];
        out[j] = f2bf(elu_f(s * dn + bias[j]));
    }
}

// ---------------- layer-2 gather (wave/node, 4 edge slots) + combine + elu + L2 norm ----------------
__global__ __launch_bounds__(256) void gather2_k(
    const int* __restrict__ starts, const int* __restrict__ cnt,
    const int* __restrict__ srclist, const unsigned short* __restrict__ c,
    const float* __restrict__ w2, const float* __restrict__ dis,
    const float* __restrict__ bias, float* __restrict__ hout)
{
    __shared__ float aggS[4][36];

    const int t = threadIdx.x;
    const int nn   = t >> 6;
    const int lane = t & 63;
    const int q    = lane & 15;
    const int slot = lane >> 4;
    const int n    = blockIdx.x * 4 + nn;

    const int s0 = starts[n];
    const int cn = cnt[n];
    float a0 = 0.f, a1 = 0.f;
    if (slot == 0) {
        unsigned int u = *(const unsigned int*)(c + (size_t)n * 32 + q * 2);
        a0 = bf2f(u & 0xffff); a1 = bf2f(u >> 16);
    }
    for (int j = slot; j < cn; j += 4) {
        int src = srclist[s0 + j];
        unsigned int u = *(const unsigned int*)(c + (size_t)src * 32 + q * 2);
        a0 += bf2f(u & 0xffff); a1 += bf2f(u >> 16);
    }
    a0 += __shfl_xor(a0, 16, 64); a0 += __shfl_xor(a0, 32, 64);
    a1 += __shfl_xor(a1, 16, 64); a1 += __shfl_xor(a1, 32, 64);
    if (slot == 0) {
        aggS[nn][q * 2 + 0] = a0;
        aggS[nn][q * 2 + 1] = a1;
    }
    __syncthreads();

    const float dn = dis[n];
    const int hh = lane >> 3, f = lane & 7;
    float4 wv = *(const float4*)(w2 + (size_t)n * 32 + hh * 4);
    float s = wv.x * aggS[nn][0 * 8 + f] + wv.y * aggS[nn][1 * 8 + f]
            + wv.z * aggS[nn][2 * 8 + f] + wv.w * aggS[nn][3 * 8 + f];
    float sv = elu_f(s * dn + bias[lane]);

    float tot = sv * sv;
    #pragma unroll
    for (int o = 1; o < 64; o <<= 1) tot += __shfl_xor(tot, o, 64);
    float inv = 1.0f / fmaxf(sqrtf(tot), 1e-12f);
    hout[(size_t)n * 64 + lane] = sv * inv;
}

// ---------------- per-graph tail: z_a, attention softmax, z_c ----------------
__global__ __launch_bounds__(128) void graph_k(const float* __restrict__ h,
                                               const float* __restrict__ z_e,
                                               const float* __restrict__ aw,
                                               const float* __restrict__ ab,
                                               const float* __restrict__ fcgw,
                                               const float* __restrict__ fcgb,
                                               const float* __restrict__ fccgw,
                                               const float* __restrict__ fccgb,
                                               float* __restrict__ z_a,
                                               float* __restrict__ z_c)
{
    __shared__ float Hs[NPG * 64];
    __shared__ float sumh[64], wsh[64], lg[NPG], ex[NPG];
    __shared__ float red[2];
    int g = blockIdx.x, t = threadIdx.x;
    const float* hg = h + (size_t)g * NPG * 64;
    for (int idx = t; idx < NPG * 64; idx += 128) Hs[idx] = hg[idx];
    __syncthreads();

    if (t < 64) {
        float s = 0.0f;
        for (int n = 0; n < NPG; ++n) s += Hs[n * 64 + t];
        sumh[t] = s;
    }
    __syncthreads();

    if (t < 64) {
        float acc = fcgb[t];
        for (int f = 0; f < 64; ++f) acc = fmaf(sumh[f], fcgw[t * 64 + f], acc);
        z_a[(size_t)g * 64 + t] = acc;
    }
    if (t < NPG) {
        float zd = 0.0f;
        for (int q = 0; q < 32; ++q) zd = fmaf(z_e[(size_t)g * 32 + q], aw[64 + q], zd);
        float dot = 0.0f;
        for (int k0 = 0; k0 < 64; ++k0) {
            int k = (k0 + t) & 63;
            dot = fmaf(Hs[t * 64 + k], aw[k], dot);
        }
        lg[t] = dot + zd + ab[0] + 1e-16f;
    }
    __syncthreads();

    if (t < 64) {
        float m = -INFINITY;
        for (int n = t; n < NPG; n += 64) m = fmaxf(m, lg[n]);
        #pragma unroll
        for (int o = 1; o < 64; o <<= 1) m = fmaxf(m, __shfl_xor(m, o, 64));
        if (t == 0) red[0] = m;
    }
    __syncthreads();
    float m = red[0];
    if (t < NPG) ex[t] = expf(lg[t] - m);
    __syncthreads();
    if (t < 64) {
        float s = 0.0f;
        for (int n = t; n < NPG; n += 64) s += ex[n];
        #pragma unroll
        for (int o = 1; o < 64; o <<= 1) s += __shfl_xor(s, o, 64);
        if (t == 0) red[1] = s + 1e-16f;
    }
    __syncthreads();
    float inv_denom = 1.0f / red[1];
    if (t < 64) {
        float a = 0.0f;
        for (int n = 0; n < NPG; ++n) a = fmaf(ex[n], Hs[n * 64 + t], a);
        wsh[t] = a * inv_denom;
    }
    __syncthreads();
    if (t < 64) {
        float acc = fccgb[t];
        for (int f = 0; f < 64; ++f) acc = fmaf(wsh[f], fccgw[t * 64 + f], acc);
        z_c[(size_t)g * 64 + t] = acc;
    }
}

extern "C" void kernel_launch(void* const* d_in, const int* in_sizes, int n_in,
                              void* d_out, int out_size, void* d_ws, size_t ws_size,
                              hipStream_t stream)
{
    const float* x     = (const float*)d_in[0];
    const int*   ei    = (const int*)d_in[1];
    const float* z_e   = (const float*)d_in[4];
    const float* nfc_w = (const float*)d_in[5];
    const float* nfc_b = (const float*)d_in[6];
    const float* g1bw  = (const float*)d_in[7];
    const float* g1cw  = (const float*)d_in[8];
    const float* g1cb  = (const float*)d_in[9];
    const float* g1b   = (const float*)d_in[10];
    const float* g2bw  = (const float*)d_in[11];
    const float* g2cw  = (const float*)d_in[12];
    const float* g2cb  = (const float*)d_in[13];
    const float* g2b   = (const float*)d_in[14];
    const float* aw    = (const float*)d_in[15];
    const float* ab    = (const float*)d_in[16];
    const float* fcgw  = (const float*)d_in[17];
    const float* fcgb  = (const float*)d_in[18];
    const float* fccgw = (const float*)d_in[19];
    const float* fccgb = (const float*)d_in[20];

    // workspace layout — every offset a multiple of 64 floats (256 B)
    float* ws        = (float*)d_ws;
    float* dis       = ws;                            // 102400 fl
    int*   cnt       = (int*)(ws + 102400);           // 102400
    int*   starts    = cnt + 102400;                  // 102400
    int*   bkt_cur   = starts + 102400;               // 512
    int*   srclist   = bkt_cur + 512;                 // 2,002,048 (391*5120 rounded to 64)
    float* hbuf      = (float*)(srclist + 2002048);   // 6.4M fl: h2 bf16 [100k x 128]; pairs overlay
    float* c1f       = hbuf + 6400000;                // 3.2M fl: b1 bf16 [100k x 64] (256B-aligned)
    float* w1        = c1f + 3200000;                 // 3.2M fl
    float* c2f       = w1 + 3200000;                  // 1.6M fl: c2 bf16 [100k x 32]
    float* w2        = c2f + 1600000;                 // 3.2M fl
    unsigned short* wb = (unsigned short*)(w2 + 3200000);  // 28672 bf16 weights
    unsigned int*  pairs = (unsigned int*)hbuf;       // 8MB (<= 25.6MB region), dead before hb
    unsigned short* hb = (unsigned short*)hbuf;
    unsigned short* c1 = (unsigned short*)c1f;
    unsigned short* c2 = (unsigned short*)c2f;

    float* z_a  = (float*)d_out;
    float* z_c  = z_a + (size_t)N_GRAPHS * 64;
    float* hout = z_a + (size_t)2 * N_GRAPHS * 64;

    // setup: bucket cursors + weight bf16 conversion (57 blocks x 512)
    setup_k<<<57, 512, 0, stream>>>(bkt_cur, nfc_w, g1bw, g1cw, g2bw, g2cw, wb);
    // merged: binscatter (first; 98 fat blocks) || fusedA (x -> h1 -> b1,w1)
    scatterA_k<<<NBE + GBA, 256, 0, stream>>>(x, wb, nfc_b, g1cb, c1, w1, N_NODES,
                                              ei, bkt_cur, pairs);
    // bucket CSR: per-node starts/cnt/dis + srclist
    bucket_csr_k<<<NBKT, 256, 0, stream>>>(pairs, bkt_cur, starts, cnt, dis, srclist);
    // h2 = elu(dis_n * (W1 . (dis_n*b_n + sum dis_src*b_src)) + g1_bias) -> bf16 (hb)
    gather1_k<<<N_NODES / 4, 256, 0, stream>>>(starts, cnt, srclist, c1, w1, dis, g1b, hb);
    // fused: c2 = dis*(h2@g2bw^T) bf16 ; w2 = h2@g2cw^T + g2cb fp32
    mgemmL2_k<<<GBA, 256, 0, stream>>>(hb, wb, g2cb, dis, c2, w2, N_NODES);
    // h = normalize(elu(dis * combine(w2, gather(c2)) + g2_bias))
    gather2_k<<<N_NODES / 4, 256, 0, stream>>>(starts, cnt, srclist, c2, w2, dis, g2b, hout);
    // per-graph pooling + attention heads
    graph_k<<<N_GRAPHS, 128, 0, stream>>>(hout, z_e, aw, ab, fcgw, fcgb, fccgw, fccgb, z_a, z_c);
}